// Round 7
// baseline (365.636 us; speedup 1.0000x reference)
//
#include <hip/hip_runtime.h>
#include <hip/hip_cooperative_groups.h>
#include <math.h>

// Problem dims (fixed by setup_inputs): inp [1,2,48,160,160] f32, target [1,48,160,160] i32
#define D_ 48
#define H_ 160
#define W_ 160
#define HW_ 25600
#define N_ 1228800
#define GBLK 480           // cooperative grid: 480 blocks x 256 thr x 10 elems = N_
#define EPT 10
#define K1_ 1216512u       // 1-based rank of sorted index floor(0.99*(N-1)); frac==0 in f32 (R1: absmax 0.0)

static_assert(N_ == GBLK * 256 * EPT, "grid");
static_assert(N_ == D_ * HW_, "dims");

// ---- workspace layout (bytes) ----
#define OFF_FA   0u
#define OFF_FB   (N_ * 4u)
#define OFF_CAND (2u * N_ * 4u)            // worst-case capacity
#define OFF_G1   (3u * N_ * 4u)            // 4096 u32
#define OFF_SC   (OFF_G1 + 4096u * 4u)     // 16 u32 scalars
#define OFF_PS   (OFF_SC + 64u)
#define OFF_PC   (OFF_PS + GBLK * 4u)
// sc: [0]=b1 [1]=rank-in-bucket [6]=thr bits [8]=candCount

namespace cg = cooperative_groups;

__device__ __forceinline__ unsigned fkey(float v) {
  unsigned u = __float_as_uint(v);
  return (u & 0x80000000u) ? ~u : (u | 0x80000000u);  // monotone map: float asc -> uint asc
}

// Single cooperative kernel. LDS map (7176 u32 = 28.7 KB):
//   smem[0..4095]    : P1 block histogram / P4 sel23 hist / P5-P6 reduce scratch
//   smem[4096..4351] : scan buffer (sel1/compact/sel23)
//   smem[4352..4607] : h2 (sel23)
//   smem[4608..4615] : scalars (sbase, sBA, sKB)
//   smem[4616..7175] : klds — per-block kl values, persist P1 -> P5 (block stays resident)
__global__ __launch_bounds__(256, 2) void k_fused(const float* __restrict__ inp,
                                                  const int* __restrict__ tgt,
                                                  float* __restrict__ fA,
                                                  float* __restrict__ fB,
                                                  unsigned* __restrict__ cand,
                                                  unsigned* __restrict__ g1,
                                                  unsigned* __restrict__ sc,
                                                  float* __restrict__ ps,
                                                  unsigned* __restrict__ pc,
                                                  float* __restrict__ out) {
  cg::grid_group grid = cg::this_grid();
  const int tid = threadIdx.x;
  const int blk = blockIdx.x;
  const int base = blk * (256 * EPT);
  __shared__ unsigned smem[7176];
  unsigned* scanb = smem + 4096;
  float* klds = (float*)(smem + 4616);

  // ---------------- P0: zero g1 + scalars ----------------
  {
    const int i = blk * 256 + tid;
    if (i < 4096) g1[i] = 0u;
    else if (i < 4112) sc[i - 4096] = 0u;
  }
  grid.sync();

  // ---------------- P1: kl_vals (-> LDS) + f0 + hi-12 histogram ----------------
  {
    for (int i = tid; i < 4096; i += 256) smem[i] = 0;
    __syncthreads();
    for (int e = 0; e < EPT; e++) {
      const int idx = base + e * 256 + tid;
      const int ww = idx % W_;
      const int hh = (idx / W_) % H_;
      const int dd = idx / HW_;
      const float p0 = inp[idx];
      const float p1 = inp[N_ + idx];
      float klh = -1.0f, klv = -1.0f, kld = -1.0f;
      if (ww < W_ - 1) {
        const float t0 = inp[idx + 1], t1 = inp[N_ + idx + 1];
        const float a0 = (t0 > 0.f) ? t0 * logf(t0) : 0.f;
        const float a1 = (t1 > 0.f) ? t1 * logf(t1) : 0.f;
        klh = 0.5f * ((a0 - t0 * p0) + (a1 - t1 * p1));
      }
      if (hh < H_ - 1) {
        const float t0 = inp[idx + W_], t1 = inp[N_ + idx + W_];
        const float a0 = (t0 > 0.f) ? t0 * logf(t0) : 0.f;
        const float a1 = (t1 > 0.f) ? t1 * logf(t1) : 0.f;
        klv = 0.5f * ((a0 - t0 * p0) + (a1 - t1 * p1));
      }
      if (dd < D_ - 1) {
        const float t0 = inp[idx + HW_], t1 = inp[N_ + idx + HW_];
        const float a0 = (t0 > 0.f) ? t0 * logf(t0) : 0.f;
        const float a1 = (t1 > 0.f) ? t1 * logf(t1) : 0.f;
        kld = 0.5f * ((a0 - t0 * p0) + (a1 - t1 * p1));
      }
      const float km = fmaxf(fmaxf(klh, klv), kld);
      klds[e * 256 + tid] = km;
      atomicAdd(&smem[fkey(km) >> 20], 1u);
      const int tv = tgt[idx];
      const int t1v = (ww < W_ - 1) ? tgt[idx + 1] : 0;
      const int t2v = (hh < H_ - 1) ? tgt[idx + W_] : 0;
      const int t3v = (dd < D_ - 1) ? tgt[idx + HW_] : 0;
      fA[idx] = (3 * tv != t1v + t2v + t3v) ? 0.f : 1e10f;
    }
    __syncthreads();
    for (int i = tid; i < 4096; i += 256) {
      const unsigned c = smem[i];
      if (c) atomicAdd(&g1[i], c);
    }
  }
  grid.sync();

  // ---------------- P2: EDT axis D (fA->fB) + sel1 in block 0 ----------------
  // Early-exit scan is bit-exact vs brute force: f>=0 => RN(f[j]+r^2) >= r^2, so once
  // r^2 >= m no candidate can lower the min; min over a set is order-independent.
  for (int e = 0; e < EPT; e++) {
    const int idx = base + e * 256 + tid;
    const int pos = idx / HW_;
    float m = fA[idx];
    for (int r = 1; r < D_; r++) {
      const float r2 = (float)(r * r);
      if (r2 >= m) break;
      const bool okm = (pos - r >= 0), okp = (pos + r < D_);
      if (!okm && !okp) break;
      if (okm) m = fminf(m, fA[idx - r * HW_] + r2);
      if (okp) m = fminf(m, fA[idx + r * HW_] + r2);
    }
    fB[idx] = m;
  }
  if (blk == 0) {
    unsigned s = 0;
#pragma unroll
    for (int i = 0; i < 16; i++) s += g1[tid * 16 + i];
    const unsigned mine = s;
    scanb[tid] = s;
    __syncthreads();
    for (int o = 1; o < 256; o <<= 1) {
      const unsigned add = (tid >= o) ? scanb[tid - o] : 0u;
      __syncthreads();
      scanb[tid] += add;
      __syncthreads();
    }
    const unsigned before = scanb[tid] - mine;
    if (before < K1_ && K1_ <= before + mine) {
      unsigned cum = before;
      for (int i = 0; i < 16; i++) {
        const unsigned c = g1[tid * 16 + i];
        if (cum < K1_ && K1_ <= cum + c) { sc[0] = (unsigned)(tid * 16 + i); sc[1] = K1_ - cum; break; }
        cum += c;
      }
    }
  }
  grid.sync();

  // ---------------- P3: EDT axis H (fB->fA) + aggregated bucket-b1 compaction ----------------
  {
    const unsigned b1 = sc[0];
    unsigned kmask = 0u;
    for (int e = 0; e < EPT; e++) {
      const int idx = base + e * 256 + tid;
      const int pos = (idx / W_) % H_;
      float m = fB[idx];
      for (int r = 1; r < H_; r++) {
        const float r2 = (float)(r * r);
        if (r2 >= m) break;
        const bool okm = (pos - r >= 0), okp = (pos + r < H_);
        if (!okm && !okp) break;
        if (okm) m = fminf(m, fB[idx - r * W_] + r2);
        if (okp) m = fminf(m, fB[idx + r * W_] + r2);
      }
      fA[idx] = m;
      if ((fkey(klds[e * 256 + tid]) >> 20) == b1) kmask |= (1u << e);
    }
    const unsigned cnt = (unsigned)__popc(kmask);
    scanb[tid] = cnt;
    __syncthreads();
    for (int o = 1; o < 256; o <<= 1) {
      const unsigned add = (tid >= o) ? scanb[tid - o] : 0u;
      __syncthreads();
      scanb[tid] += add;
      __syncthreads();
    }
    if (tid == 255 && scanb[255] > 0) smem[4608] = atomicAdd(&sc[8], scanb[255]);
    __syncthreads();
    if (cnt) {
      unsigned wb = smem[4608] + scanb[tid] - cnt;
      for (int e = 0; e < EPT; e++) {
        if (kmask & (1u << e)) cand[wb++] = fkey(klds[e * 256 + tid]) & 0xFFFFFu;
      }
    }
  }
  grid.sync();

  // ---------------- P4: EDT axis W + sqrt (fA->fB) + sel23 in block 0 ----------------
  for (int e = 0; e < EPT; e++) {
    const int idx = base + e * 256 + tid;
    const int pos = idx % W_;
    float m = fA[idx];
    for (int r = 1; r < W_; r++) {
      const float r2 = (float)(r * r);
      if (r2 >= m) break;
      const bool okm = (pos - r >= 0), okp = (pos + r < W_);
      if (!okm && !okp) break;
      if (okm) m = fminf(m, fA[idx - r] + r2);
      if (okp) m = fminf(m, fA[idx + r] + r2);
    }
    fB[idx] = sqrtf(m);
  }
  if (blk == 0) {
    const unsigned M = sc[8];
    const unsigned K = sc[1];
    unsigned* hist = smem;           // 4096
    unsigned* h2 = smem + 4352;      // 256
    for (int i = tid; i < 4096; i += 256) hist[i] = 0;
    h2[tid] = 0;
    __syncthreads();
    const unsigned M4 = M & ~3u;
    for (unsigned g = (unsigned)tid; g * 4u < M4; g += 256u) {
      const uint4 v = *reinterpret_cast<const uint4*>(&cand[g * 4u]);
      atomicAdd(&hist[(v.x >> 8) & 0xFFFu], 1u);
      atomicAdd(&hist[(v.y >> 8) & 0xFFFu], 1u);
      atomicAdd(&hist[(v.z >> 8) & 0xFFFu], 1u);
      atomicAdd(&hist[(v.w >> 8) & 0xFFFu], 1u);
    }
    for (unsigned i = M4 + (unsigned)tid; i < M; i += 256u) atomicAdd(&hist[(cand[i] >> 8) & 0xFFFu], 1u);
    __syncthreads();
    unsigned mine = 0;
#pragma unroll
    for (int i = 0; i < 16; i++) mine += hist[tid * 16 + i];
    scanb[tid] = mine;
    __syncthreads();
    for (int o = 1; o < 256; o <<= 1) {
      const unsigned add = (tid >= o) ? scanb[tid - o] : 0u;
      __syncthreads();
      scanb[tid] += add;
      __syncthreads();
    }
    {
      const unsigned before = scanb[tid] - mine;
      if (before < K && K <= before + mine) {
        unsigned cum = before;
        for (int i = 0; i < 16; i++) {
          const unsigned c = hist[tid * 16 + i];
          if (cum < K && K <= cum + c) { smem[4609] = (unsigned)(tid * 16 + i); smem[4610] = K - cum; break; }
          cum += c;
        }
      }
    }
    __syncthreads();
    const unsigned bA = smem[4609], KB = smem[4610];
    for (unsigned g = (unsigned)tid; g * 4u < M4; g += 256u) {
      const uint4 v = *reinterpret_cast<const uint4*>(&cand[g * 4u]);
      if (((v.x >> 8) & 0xFFFu) == bA) atomicAdd(&h2[v.x & 0xFFu], 1u);
      if (((v.y >> 8) & 0xFFFu) == bA) atomicAdd(&h2[v.y & 0xFFu], 1u);
      if (((v.z >> 8) & 0xFFFu) == bA) atomicAdd(&h2[v.z & 0xFFu], 1u);
      if (((v.w >> 8) & 0xFFFu) == bA) atomicAdd(&h2[v.w & 0xFFu], 1u);
    }
    for (unsigned i = M4 + (unsigned)tid; i < M; i += 256u) {
      const unsigned v = cand[i];
      if (((v >> 8) & 0xFFFu) == bA) atomicAdd(&h2[v & 0xFFu], 1u);
    }
    __syncthreads();
    const unsigned mine2 = h2[tid];
    scanb[tid] = mine2;
    __syncthreads();
    for (int o = 1; o < 256; o <<= 1) {
      const unsigned add = (tid >= o) ? scanb[tid - o] : 0u;
      __syncthreads();
      scanb[tid] += add;
      __syncthreads();
    }
    {
      const unsigned before = scanb[tid] - mine2;
      if (before < KB && KB <= before + mine2) {
        const unsigned key = (sc[0] << 20) | (bA << 8) | (unsigned)tid;
        sc[6] = (key & 0x80000000u) ? (key & 0x7FFFFFFFu) : ~key;  // inverse of fkey
      }
    }
  }
  grid.sync();

  // ---------------- P5: masked loss + block partial ----------------
  {
    const float thr = __uint_as_float(sc[6]);
    float myloss = 0.f;
    unsigned mycnt = 0u;
    for (int e = 0; e < EPT; e++) {
      const int idx = base + e * 256 + tid;
      if (klds[e * 256 + tid] < thr) continue;
      mycnt++;
      const float g = fB[idx];
      if (g == 0.f) continue;
      const int ww = idx % W_;
      const int hh = (idx / W_) % H_;
      const int dd = idx / HW_;
      const float p0 = inp[idx];
      const float p1 = inp[N_ + idx];
      // DIRECTIONS in torch-loop order: i outer, j mid, k inner, skipping (0,0,0)
      constexpr int DI[26] = {-1,-1,-1,-1,-1,-1,-1,-1,-1, 0,0,0,0,0,0,0,0, 1,1,1,1,1,1,1,1,1};
      constexpr int DJ[26] = {-1,-1,-1, 0,0,0, 1,1,1, -1,-1,-1, 0,0, 1,1,1, -1,-1,-1, 0,0,0, 1,1,1};
      constexpr int DK[26] = {-1,0,1, -1,0,1, -1,0,1, -1,0,1, -1,1, -1,0,1, -1,0,1, -1,0,1, -1,0,1};
      float klv[26], dst[26];
      float s = 0.f;
#pragma unroll
      for (int t = 0; t < 26; t++) {
        const int nd = dd + DI[t], nh = hh + DJ[t], nw = ww + DK[t];
        const bool inb = ((unsigned)nd < (unsigned)D_) && ((unsigned)nh < (unsigned)H_) &&
                         ((unsigned)nw < (unsigned)W_);
        const int nidx = (nd * H_ + nh) * W_ + nw;
        dst[t] = inb ? fB[nidx] : 0.f;
        // coordinate masks from the reference's (batch,d,h) indexing bug, specialized to B=1:
        //  i==+1 -> 0; j==+1 -> 0; j==-1 -> only d==0; k==+1 -> only h==159; k==-1 -> only h==0
        bool keep;
        if (DI[t] == 1 || DJ[t] == 1) keep = false;
        else {
          keep = true;
          if (DJ[t] == -1) keep = (dd == 0);
          if (DK[t] == 1) keep = keep && (hh == H_ - 1);
          if (DK[t] == -1) keep = keep && (hh == 0);
        }
        float kt = 0.f;
        if (keep) {
          float t0 = 0.f, t1 = 0.f;
          if (inb) { t0 = inp[nidx]; t1 = inp[N_ + nidx]; }
          const float a0 = (t0 > 0.f) ? t0 * logf(t0) : 0.f;
          const float a1 = (t1 > 0.f) ? t1 * logf(t1) : 0.f;
          const float kldm = 0.5f * ((a0 - t0 * p0) + (a1 - t1 * p1));
          kt = expf(kldm);
        }
        klv[t] = kt;
        s += kt;
      }
      const float denom = (s == 0.f) ? 1.f : s;
      int amin = 0;
      float dmin = dst[0];
#pragma unroll
      for (int t = 1; t < 26; t++) {
        if (dst[t] < dmin) { dmin = dst[t]; amin = t; }  // first-min, like jnp.argmin
      }
      const float yoff = (float)(0.2 / 26.0);
      float bsum = 0.f;
#pragma unroll
      for (int t = 0; t < 26; t++) {
        const float x = klv[t] / denom;
        const float y = (t == amin) ? 0.8f : yoff;
        bsum += fmaxf(x, 0.f) - x * y + log1pf(expf(-fabsf(x)));
      }
      myloss += (fminf(g, 20.f) / 20.f) * (bsum / 26.f);
    }
    __syncthreads();  // smem scratch handoff (sel23 aliases done)
    float* ls = (float*)smem;
    unsigned* lc = smem + 256;
    ls[tid] = myloss;
    lc[tid] = mycnt;
    __syncthreads();
    for (int o = 128; o > 0; o >>= 1) {
      if (tid < o) { ls[tid] += ls[tid + o]; lc[tid] += lc[tid + o]; }
      __syncthreads();
    }
    if (tid == 0) { ps[blk] = ls[0]; pc[blk] = lc[0]; }
  }
  grid.sync();

  // ---------------- P6: deterministic final reduce (block 0) ----------------
  if (blk == 0) {
    float* ls = (float*)smem;
    unsigned* lc = smem + 256;
    float s = ps[tid];
    unsigned c = pc[tid];
    if (tid < GBLK - 256) { s += ps[tid + 256]; c += pc[tid + 256]; }
    ls[tid] = s;
    lc[tid] = c;
    __syncthreads();
    for (int o = 128; o > 0; o >>= 1) {
      if (tid < o) { ls[tid] += ls[tid + o]; lc[tid] += lc[tid + o]; }
      __syncthreads();
    }
    if (tid == 0) out[0] = ls[0] / (float)lc[0];
  }
}

extern "C" void kernel_launch(void* const* d_in, const int* in_sizes, int n_in,
                              void* d_out, int out_size, void* d_ws, size_t ws_size,
                              hipStream_t stream) {
  (void)in_sizes; (void)n_in; (void)out_size; (void)ws_size;
  const float* inp = (const float*)d_in[0];
  const int* tgt = (const int*)d_in[1];
  float* out = (float*)d_out;
  char* ws = (char*)d_ws;

  float* fA = (float*)(ws + OFF_FA);
  float* fB = (float*)(ws + OFF_FB);
  unsigned* cand = (unsigned*)(ws + OFF_CAND);
  unsigned* g1 = (unsigned*)(ws + OFF_G1);
  unsigned* sc = (unsigned*)(ws + OFF_SC);
  float* ps = (float*)(ws + OFF_PS);
  unsigned* pc = (unsigned*)(ws + OFF_PC);

  void* kArgs[] = {(void*)&inp, (void*)&tgt, (void*)&fA, (void*)&fB, (void*)&cand,
                   (void*)&g1, (void*)&sc, (void*)&ps, (void*)&pc, (void*)&out};
  hipLaunchCooperativeKernel((const void*)k_fused, dim3(GBLK), dim3(256), kArgs, 0, stream);
}

// Round 8
// 106.250 us; speedup vs baseline: 3.4413x; 3.4413x over previous
//
#include <hip/hip_runtime.h>
#include <math.h>

// Problem dims (fixed by setup_inputs): inp [1,2,48,160,160] f32, target [1,48,160,160] i32
#define D_ 48
#define H_ 160
#define W_ 160
#define HW_ 25600
#define N_ 1228800
#define NBLK 4800          // N_/256, 1 voxel/thread (high-TLP: ~19K waves)
#define HBLK 600           // k_prep only (8 elems/thread, LDS-hist amortized)
#define K1_ 1216512u       // 1-based rank of sorted index floor(0.99*(N-1)); frac==0 in f32 (R1: absmax 0.0)

static_assert(N_ == D_ * HW_, "dims");
static_assert(N_ == NBLK * 256, "grid");
static_assert(N_ == HBLK * 256 * 8, "hist grid");

// ---- workspace layout (bytes) ----
#define OFF_KL   0u
#define OFF_FA   (N_ * 4u)
#define OFF_FB   (2u * N_ * 4u)
#define OFF_CAND (3u * N_ * 4u)            // per-block private regions: 256 u32 per block
#define OFF_G1   (4u * N_ * 4u)            // 4096 u32
#define OFF_SC   (OFF_G1 + 4096u * 4u)     // 16 u32 scalars
#define OFF_PS   (OFF_SC + 64u)
#define OFF_PC   (OFF_PS + NBLK * 4u)
#define OFF_CNT  (OFF_PC + NBLK * 4u)      // per-block candidate counts
// sc: [0]=b1 [1]=rank-in-bucket [6]=thr bits

__device__ __forceinline__ unsigned fkey(float v) {
  unsigned u = __float_as_uint(v);
  return (u & 0x80000000u) ? ~u : (u | 0x80000000u);  // monotone map: float asc -> uint asc
}

// ---------------- zero g1 + scalars ----------------
__global__ __launch_bounds__(256) void k_zero(unsigned* __restrict__ g1,
                                              unsigned* __restrict__ sc) {
  const int i = blockIdx.x * 256 + threadIdx.x;
  if (i < 4096) g1[i] = 0u;
  else if (i < 4112) sc[i - 4096] = 0u;
}

// ---------------- kl_vals + initial dist field + level-1 (hi-12) histogram ----------------
__global__ __launch_bounds__(256) void k_prep(const float* __restrict__ inp,
                                              const int* __restrict__ tgt,
                                              float* __restrict__ kl,
                                              float* __restrict__ f0,
                                              unsigned* __restrict__ ghist) {
  __shared__ unsigned h[4096];
  const int tid = threadIdx.x;
  for (int i = tid; i < 4096; i += 256) h[i] = 0;
  __syncthreads();
  const int base = blockIdx.x * 2048;
  for (int e = 0; e < 8; e++) {
    const int idx = base + e * 256 + tid;
    const int ww = idx % W_;
    const int hh = (idx / W_) % H_;
    const int dd = idx / HW_;
    const float p0 = inp[idx];
    const float p1 = inp[N_ + idx];

    float klh = -1.0f, klv = -1.0f, kld = -1.0f;
    if (ww < W_ - 1) {
      const float t0 = inp[idx + 1], t1 = inp[N_ + idx + 1];
      const float a0 = (t0 > 0.f) ? t0 * logf(t0) : 0.f;
      const float a1 = (t1 > 0.f) ? t1 * logf(t1) : 0.f;
      klh = 0.5f * ((a0 - t0 * p0) + (a1 - t1 * p1));
    }
    if (hh < H_ - 1) {
      const float t0 = inp[idx + W_], t1 = inp[N_ + idx + W_];
      const float a0 = (t0 > 0.f) ? t0 * logf(t0) : 0.f;
      const float a1 = (t1 > 0.f) ? t1 * logf(t1) : 0.f;
      klv = 0.5f * ((a0 - t0 * p0) + (a1 - t1 * p1));
    }
    if (dd < D_ - 1) {
      const float t0 = inp[idx + HW_], t1 = inp[N_ + idx + HW_];
      const float a0 = (t0 > 0.f) ? t0 * logf(t0) : 0.f;
      const float a1 = (t1 > 0.f) ? t1 * logf(t1) : 0.f;
      kld = 0.5f * ((a0 - t0 * p0) + (a1 - t1 * p1));
    }
    const float kmax = fmaxf(fmaxf(klh, klv), kld);
    kl[idx] = kmax;
    atomicAdd(&h[fkey(kmax) >> 20], 1u);

    const int tv = tgt[idx];
    const int t1 = (ww < W_ - 1) ? tgt[idx + 1] : 0;
    const int t2 = (hh < H_ - 1) ? tgt[idx + W_] : 0;
    const int t3 = (dd < D_ - 1) ? tgt[idx + HW_] : 0;
    f0[idx] = (3 * tv != t1 + t2 + t3) ? 0.f : 1e10f;
  }
  __syncthreads();
  for (int i = tid; i < 4096; i += 256) {
    const unsigned c = h[i];
    if (c) atomicAdd(&ghist[i], c);
  }
}

// ---------------- EDT axis D (1/thr) + level-1 rank-select in block 0 ----------------
// Early-exit scan is bit-exact vs brute force: f>=0 => RN(f[j]+r^2) >= r^2, so once r^2 >= m
// no candidate can lower the min; min over a set is order-independent.
__global__ __launch_bounds__(256) void k_dt_d(const float* __restrict__ fin,
                                              float* __restrict__ fout,
                                              const unsigned* __restrict__ g1,
                                              unsigned* __restrict__ sc) {
  const int idx = blockIdx.x * 256 + threadIdx.x;
  const int pos = idx / HW_;
  float m = fin[idx];
  for (int r = 1; r < D_; r++) {
    const float r2 = (float)(r * r);
    if (r2 >= m) break;
    const bool okm = (pos - r >= 0), okp = (pos + r < D_);
    if (!okm && !okp) break;
    if (okm) m = fminf(m, fin[idx - r * HW_] + r2);
    if (okp) m = fminf(m, fin[idx + r * HW_] + r2);
  }
  fout[idx] = m;

  if (blockIdx.x == 0) {
    __shared__ unsigned ssum[256];
    const int t = threadIdx.x;
    unsigned s = 0;
#pragma unroll
    for (int i = 0; i < 16; i++) s += g1[t * 16 + i];
    const unsigned mine = s;
    ssum[t] = s;
    __syncthreads();
    for (int o = 1; o < 256; o <<= 1) {
      const unsigned add = (t >= o) ? ssum[t - o] : 0u;
      __syncthreads();
      ssum[t] += add;
      __syncthreads();
    }
    const unsigned before = ssum[t] - mine;
    if (before < K1_ && K1_ <= before + mine) {
      unsigned cum = before;
      for (int i = 0; i < 16; i++) {
        const unsigned c = g1[t * 16 + i];
        if (cum < K1_ && K1_ <= cum + c) { sc[0] = (unsigned)(t * 16 + i); sc[1] = K1_ - cum; break; }
        cum += c;
      }
    }
  }
}

// ---------------- EDT axis H (1/thr) + atomic-free private-region compaction ----------------
// Each block writes its bucket-b1 candidates to cand[blk*256 ..] via ballot/popc prefix
// (deterministic layout, zero global atomics) and cnt[blk] via plain store.
__global__ __launch_bounds__(256) void k_dt_h(const float* __restrict__ fin,
                                              float* __restrict__ fout,
                                              const float* __restrict__ kl,
                                              unsigned* __restrict__ cand,
                                              unsigned* __restrict__ cnt,
                                              const unsigned* __restrict__ sc) {
  const int tid = threadIdx.x;
  const int idx = blockIdx.x * 256 + tid;
  const int pos = (idx / W_) % H_;
  float m = fin[idx];
  for (int r = 1; r < H_; r++) {
    const float r2 = (float)(r * r);
    if (r2 >= m) break;
    const bool okm = (pos - r >= 0), okp = (pos + r < H_);
    if (!okm && !okp) break;
    if (okm) m = fminf(m, fin[idx - r * W_] + r2);
    if (okp) m = fminf(m, fin[idx + r * W_] + r2);
  }
  fout[idx] = m;

  const unsigned key = fkey(kl[idx]);
  const bool has = ((key >> 20) == sc[0]);
  const unsigned long long bal = __ballot(has);
  const int lane = tid & 63;
  const int wid = tid >> 6;
  const unsigned lpre = (unsigned)__popcll(bal & ((1ULL << lane) - 1ULL));
  const unsigned wtot = (unsigned)__popcll(bal);
  __shared__ unsigned wcnt[4];
  if (lane == 0) wcnt[wid] = wtot;
  __syncthreads();
  unsigned off = 0;
  for (int w = 0; w < wid; w++) off += wcnt[w];
  if (has) cand[blockIdx.x * 256 + off + lpre] = key & 0xFFFFFu;
  if (tid == 0) cnt[blockIdx.x] = wcnt[0] + wcnt[1] + wcnt[2] + wcnt[3];
}

// ---------------- EDT axis W + sqrt (1/thr) + 12+8 radix select in block 0 ----------------
__global__ __launch_bounds__(256) void k_dt_w(const float* __restrict__ fin,
                                              float* __restrict__ fout,
                                              const unsigned* __restrict__ cand,
                                              const unsigned* __restrict__ cnt,
                                              unsigned* __restrict__ sc) {
  const int idx = blockIdx.x * 256 + threadIdx.x;
  const int pos = idx % W_;
  float m = fin[idx];
  for (int r = 1; r < W_; r++) {
    const float r2 = (float)(r * r);
    if (r2 >= m) break;
    const bool okm = (pos - r >= 0), okp = (pos + r < W_);
    if (!okm && !okp) break;
    if (okm) m = fminf(m, fin[idx - r] + r2);
    if (okp) m = fminf(m, fin[idx + r] + r2);
  }
  fout[idx] = sqrtf(m);

  if (blockIdx.x != 0) return;
  // ---- block 0 tail: rank-select over the private-region candidates (ready last kernel) ----
  const int tid = threadIdx.x;
  const unsigned K = sc[1];
  __shared__ unsigned hist[4096];
  __shared__ unsigned ssum[256];
  __shared__ unsigned h2[256];
  __shared__ unsigned sBA, sKB;
  for (int i = tid; i < 4096; i += 256) hist[i] = 0;
  h2[tid] = 0;
  __syncthreads();
  for (int b = tid; b < NBLK; b += 256) {
    const unsigned c = cnt[b];
    const unsigned rb = (unsigned)b * 256u;
    for (unsigned i = 0; i < c; i++) atomicAdd(&hist[(cand[rb + i] >> 8) & 0xFFFu], 1u);
  }
  __syncthreads();
  unsigned mine = 0;
#pragma unroll
  for (int i = 0; i < 16; i++) mine += hist[tid * 16 + i];
  ssum[tid] = mine;
  __syncthreads();
  for (int o = 1; o < 256; o <<= 1) {
    const unsigned add = (tid >= o) ? ssum[tid - o] : 0u;
    __syncthreads();
    ssum[tid] += add;
    __syncthreads();
  }
  {
    const unsigned before = ssum[tid] - mine;
    if (before < K && K <= before + mine) {
      unsigned cum = before;
      for (int i = 0; i < 16; i++) {
        const unsigned c = hist[tid * 16 + i];
        if (cum < K && K <= cum + c) { sBA = (unsigned)(tid * 16 + i); sKB = K - cum; break; }
        cum += c;
      }
    }
  }
  __syncthreads();
  const unsigned bA = sBA, KB = sKB;
  for (int b = tid; b < NBLK; b += 256) {
    const unsigned c = cnt[b];
    const unsigned rb = (unsigned)b * 256u;
    for (unsigned i = 0; i < c; i++) {
      const unsigned v = cand[rb + i];
      if (((v >> 8) & 0xFFFu) == bA) atomicAdd(&h2[v & 0xFFu], 1u);
    }
  }
  __syncthreads();
  const unsigned mine2 = h2[tid];
  ssum[tid] = mine2;
  __syncthreads();
  for (int o = 1; o < 256; o <<= 1) {
    const unsigned add = (tid >= o) ? ssum[tid - o] : 0u;
    __syncthreads();
    ssum[tid] += add;
    __syncthreads();
  }
  {
    const unsigned before = ssum[tid] - mine2;
    if (before < KB && KB <= before + mine2) {
      const unsigned key = (sc[0] << 20) | (bA << 8) | (unsigned)tid;
      sc[6] = (key & 0x80000000u) ? (key & 0x7FFFFFFFu) : ~key;  // inverse of fkey
    }
  }
}

// ---------------- masked loss at each voxel + block partials (plain stores) ----------------
__global__ __launch_bounds__(256) void k_loss(const float* __restrict__ inp,
                                              const float* __restrict__ kl,
                                              const float* __restrict__ gdist,
                                              const unsigned* __restrict__ sc,
                                              float* __restrict__ psum,
                                              unsigned* __restrict__ pcnt) {
  const int tid = threadIdx.x;
  const int idx = blockIdx.x * 256 + tid;
  const float thr = __uint_as_float(sc[6]);
  float myloss = 0.f;
  unsigned mycnt = 0u;
  if (kl[idx] >= thr) {
    mycnt = 1u;
    const float g = gdist[idx];
    if (g != 0.f) {
      const int ww = idx % W_;
      const int hh = (idx / W_) % H_;
      const int dd = idx / HW_;
      const float p0 = inp[idx];
      const float p1 = inp[N_ + idx];
      // DIRECTIONS in torch-loop order: i outer, j mid, k inner, skipping (0,0,0)
      constexpr int DI[26] = {-1,-1,-1,-1,-1,-1,-1,-1,-1, 0,0,0,0,0,0,0,0, 1,1,1,1,1,1,1,1,1};
      constexpr int DJ[26] = {-1,-1,-1, 0,0,0, 1,1,1, -1,-1,-1, 0,0, 1,1,1, -1,-1,-1, 0,0,0, 1,1,1};
      constexpr int DK[26] = {-1,0,1, -1,0,1, -1,0,1, -1,0,1, -1,1, -1,0,1, -1,0,1, -1,0,1, -1,0,1};
      float klv[26], dst[26];
      float s = 0.f;
#pragma unroll
      for (int t = 0; t < 26; t++) {
        const int nd = dd + DI[t], nh = hh + DJ[t], nw = ww + DK[t];
        const bool inb = ((unsigned)nd < (unsigned)D_) && ((unsigned)nh < (unsigned)H_) &&
                         ((unsigned)nw < (unsigned)W_);
        const int nidx = (nd * H_ + nh) * W_ + nw;
        dst[t] = inb ? gdist[nidx] : 0.f;
        // coordinate masks from the reference's (batch,d,h) indexing bug, specialized to B=1:
        //  i==+1 -> 0; j==+1 -> 0; j==-1 -> only d==0; k==+1 -> only h==159; k==-1 -> only h==0
        bool keep;
        if (DI[t] == 1 || DJ[t] == 1) keep = false;
        else {
          keep = true;
          if (DJ[t] == -1) keep = (dd == 0);
          if (DK[t] == 1) keep = keep && (hh == H_ - 1);
          if (DK[t] == -1) keep = keep && (hh == 0);
        }
        float kt = 0.f;
        if (keep) {
          float t0 = 0.f, t1 = 0.f;
          if (inb) { t0 = inp[nidx]; t1 = inp[N_ + nidx]; }
          const float a0 = (t0 > 0.f) ? t0 * logf(t0) : 0.f;
          const float a1 = (t1 > 0.f) ? t1 * logf(t1) : 0.f;
          const float kldm = 0.5f * ((a0 - t0 * p0) + (a1 - t1 * p1));
          kt = expf(kldm);
        }
        klv[t] = kt;
        s += kt;
      }
      const float denom = (s == 0.f) ? 1.f : s;
      int amin = 0;
      float dmin = dst[0];
#pragma unroll
      for (int t = 1; t < 26; t++) {
        if (dst[t] < dmin) { dmin = dst[t]; amin = t; }  // first-min, like jnp.argmin
      }
      const float yoff = (float)(0.2 / 26.0);
      float bsum = 0.f;
#pragma unroll
      for (int t = 0; t < 26; t++) {
        const float x = klv[t] / denom;
        const float y = (t == amin) ? 0.8f : yoff;
        bsum += fmaxf(x, 0.f) - x * y + log1pf(expf(-fabsf(x)));
      }
      myloss = (fminf(g, 20.f) / 20.f) * (bsum / 26.f);
    }
  }
  __shared__ float ls[256];
  __shared__ unsigned lc[256];
  ls[tid] = myloss;
  lc[tid] = mycnt;
  __syncthreads();
  for (int o = 128; o > 0; o >>= 1) {
    if (tid < o) { ls[tid] += ls[tid + o]; lc[tid] += lc[tid + o]; }
    __syncthreads();
  }
  if (tid == 0) { psum[blockIdx.x] = ls[0]; pcnt[blockIdx.x] = lc[0]; }
}

// ---------------- deterministic final reduce (1 block, vectorized) ----------------
__global__ __launch_bounds__(256) void k_reduce(const float* __restrict__ psum,
                                                const unsigned* __restrict__ pcnt,
                                                float* __restrict__ out) {
  __shared__ float ls[256];
  __shared__ unsigned lc[256];
  const int t = threadIdx.x;
  float s = 0.f;
  unsigned c = 0;
  for (int g = t; g * 4 < NBLK; g += 256) {
    const float4 s4 = *reinterpret_cast<const float4*>(&psum[g * 4]);
    const uint4 c4 = *reinterpret_cast<const uint4*>(&pcnt[g * 4]);
    s += (s4.x + s4.y) + (s4.z + s4.w);
    c += c4.x + c4.y + c4.z + c4.w;
  }
  ls[t] = s;
  lc[t] = c;
  __syncthreads();
  for (int o = 128; o > 0; o >>= 1) {
    if (t < o) { ls[t] += ls[t + o]; lc[t] += lc[t + o]; }
    __syncthreads();
  }
  if (t == 0) out[0] = ls[0] / (float)lc[0];
}

extern "C" void kernel_launch(void* const* d_in, const int* in_sizes, int n_in,
                              void* d_out, int out_size, void* d_ws, size_t ws_size,
                              hipStream_t stream) {
  (void)in_sizes; (void)n_in; (void)out_size; (void)ws_size;
  const float* inp = (const float*)d_in[0];
  const int* tgt = (const int*)d_in[1];
  float* out = (float*)d_out;
  char* ws = (char*)d_ws;

  float* kl = (float*)(ws + OFF_KL);
  float* fA = (float*)(ws + OFF_FA);
  float* fB = (float*)(ws + OFF_FB);
  unsigned* cand = (unsigned*)(ws + OFF_CAND);
  unsigned* g1 = (unsigned*)(ws + OFF_G1);
  unsigned* sc = (unsigned*)(ws + OFF_SC);
  float* ps = (float*)(ws + OFF_PS);
  unsigned* pc = (unsigned*)(ws + OFF_PC);
  unsigned* cnt = (unsigned*)(ws + OFF_CNT);

  k_zero<<<17, 256, 0, stream>>>(g1, sc);
  k_prep<<<HBLK, 256, 0, stream>>>(inp, tgt, kl, fA, g1);
  k_dt_d<<<NBLK, 256, 0, stream>>>(fA, fB, g1, sc);            // EDT D + sel1 (blk0)
  k_dt_h<<<NBLK, 256, 0, stream>>>(fB, fA, kl, cand, cnt, sc); // EDT H + atomic-free compaction
  k_dt_w<<<NBLK, 256, 0, stream>>>(fA, fB, cand, cnt, sc);     // EDT W + sqrt + sel23 (blk0)
  k_loss<<<NBLK, 256, 0, stream>>>(inp, kl, fB, sc, ps, pc);
  k_reduce<<<1, 256, 0, stream>>>(ps, pc, out);
}

// Round 9
// 102.128 us; speedup vs baseline: 3.5802x; 1.0404x over previous
//
#include <hip/hip_runtime.h>
#include <math.h>

// Problem dims (fixed by setup_inputs): inp [1,2,48,160,160] f32, target [1,48,160,160] i32
#define D_ 48
#define H_ 160
#define W_ 160
#define HW_ 25600
#define N_ 1228800
#define NBLK 4800          // N_/256, 1 voxel/thread (high-TLP)
#define HBLK 600           // k_prep only (8 elems/thread, LDS-hist amortized)
#define REGCAP (N_ / 8)    // dense compaction region size (8 regions, one per 600-block group)
#define K1_ 1216512u       // 1-based rank of sorted index floor(0.99*(N-1)); frac==0 in f32 (R1: absmax 0.0)

static_assert(N_ == D_ * HW_, "dims");
static_assert(N_ == NBLK * 256, "grid");
static_assert(N_ == HBLK * 256 * 8, "hist grid");

// ---- workspace layout (bytes) ----
#define OFF_KL   0u
#define OFF_FA   (N_ * 4u)
#define OFF_FB   (2u * N_ * 4u)
#define OFF_CAND (3u * N_ * 4u)            // 8 regions x REGCAP u32 (capacity-safe by construction)
#define OFF_G1   (4u * N_ * 4u)            // 4096 u32
#define OFF_SC   (OFF_G1 + 4096u * 4u)     // 16 u32 scalars
#define OFF_PS   (OFF_SC + 64u)
#define OFF_PC   (OFF_PS + NBLK * 4u)
// sc: [0]=b1 [1]=rank-in-bucket [6]=thr bits [8..15]=per-region candidate counts

__device__ __forceinline__ unsigned fkey(float v) {
  unsigned u = __float_as_uint(v);
  return (u & 0x80000000u) ? ~u : (u | 0x80000000u);  // monotone map: float asc -> uint asc
}

// ---------------- zero g1 + scalars ----------------
__global__ __launch_bounds__(256) void k_zero(unsigned* __restrict__ g1,
                                              unsigned* __restrict__ sc) {
  const int i = blockIdx.x * 256 + threadIdx.x;
  if (i < 4096) g1[i] = 0u;
  else if (i < 4112) sc[i - 4096] = 0u;
}

// ---------------- kl_vals + initial dist field + level-1 (hi-12) histogram ----------------
__global__ __launch_bounds__(256) void k_prep(const float* __restrict__ inp,
                                              const int* __restrict__ tgt,
                                              float* __restrict__ kl,
                                              float* __restrict__ f0,
                                              unsigned* __restrict__ ghist) {
  __shared__ unsigned h[4096];
  const int tid = threadIdx.x;
  for (int i = tid; i < 4096; i += 256) h[i] = 0;
  __syncthreads();
  const int base = blockIdx.x * 2048;
  for (int e = 0; e < 8; e++) {
    const int idx = base + e * 256 + tid;
    const int ww = idx % W_;
    const int hh = (idx / W_) % H_;
    const int dd = idx / HW_;
    const float p0 = inp[idx];
    const float p1 = inp[N_ + idx];

    float klh = -1.0f, klv = -1.0f, kld = -1.0f;
    if (ww < W_ - 1) {
      const float t0 = inp[idx + 1], t1 = inp[N_ + idx + 1];
      const float a0 = (t0 > 0.f) ? t0 * logf(t0) : 0.f;
      const float a1 = (t1 > 0.f) ? t1 * logf(t1) : 0.f;
      klh = 0.5f * ((a0 - t0 * p0) + (a1 - t1 * p1));
    }
    if (hh < H_ - 1) {
      const float t0 = inp[idx + W_], t1 = inp[N_ + idx + W_];
      const float a0 = (t0 > 0.f) ? t0 * logf(t0) : 0.f;
      const float a1 = (t1 > 0.f) ? t1 * logf(t1) : 0.f;
      klv = 0.5f * ((a0 - t0 * p0) + (a1 - t1 * p1));
    }
    if (dd < D_ - 1) {
      const float t0 = inp[idx + HW_], t1 = inp[N_ + idx + HW_];
      const float a0 = (t0 > 0.f) ? t0 * logf(t0) : 0.f;
      const float a1 = (t1 > 0.f) ? t1 * logf(t1) : 0.f;
      kld = 0.5f * ((a0 - t0 * p0) + (a1 - t1 * p1));
    }
    const float kmax = fmaxf(fmaxf(klh, klv), kld);
    kl[idx] = kmax;
    atomicAdd(&h[fkey(kmax) >> 20], 1u);

    const int tv = tgt[idx];
    const int t1 = (ww < W_ - 1) ? tgt[idx + 1] : 0;
    const int t2 = (hh < H_ - 1) ? tgt[idx + W_] : 0;
    const int t3 = (dd < D_ - 1) ? tgt[idx + HW_] : 0;
    f0[idx] = (3 * tv != t1 + t2 + t3) ? 0.f : 1e10f;
  }
  __syncthreads();
  for (int i = tid; i < 4096; i += 256) {
    const unsigned c = h[i];
    if (c) atomicAdd(&ghist[i], c);
  }
}

// ---------------- EDT axis D (1/thr) + level-1 rank-select in block 0 ----------------
// Early-exit scan is bit-exact vs brute force: f>=0 => RN(f[j]+r^2) >= r^2, so once r^2 >= m
// no candidate can lower the min; min over a set is order-independent.
__global__ __launch_bounds__(256) void k_dt_d(const float* __restrict__ fin,
                                              float* __restrict__ fout,
                                              const unsigned* __restrict__ g1,
                                              unsigned* __restrict__ sc) {
  const int idx = blockIdx.x * 256 + threadIdx.x;
  const int pos = idx / HW_;
  float m = fin[idx];
  for (int r = 1; r < D_; r++) {
    const float r2 = (float)(r * r);
    if (r2 >= m) break;
    const bool okm = (pos - r >= 0), okp = (pos + r < D_);
    if (!okm && !okp) break;
    if (okm) m = fminf(m, fin[idx - r * HW_] + r2);
    if (okp) m = fminf(m, fin[idx + r * HW_] + r2);
  }
  fout[idx] = m;

  if (blockIdx.x == 0) {
    __shared__ unsigned ssum[256];
    const int t = threadIdx.x;
    unsigned s = 0;
#pragma unroll
    for (int i = 0; i < 16; i++) s += g1[t * 16 + i];
    const unsigned mine = s;
    ssum[t] = s;
    __syncthreads();
    for (int o = 1; o < 256; o <<= 1) {
      const unsigned add = (t >= o) ? ssum[t - o] : 0u;
      __syncthreads();
      ssum[t] += add;
      __syncthreads();
    }
    const unsigned before = ssum[t] - mine;
    if (before < K1_ && K1_ <= before + mine) {
      unsigned cum = before;
      for (int i = 0; i < 16; i++) {
        const unsigned c = g1[t * 16 + i];
        if (cum < K1_ && K1_ <= cum + c) { sc[0] = (unsigned)(t * 16 + i); sc[1] = K1_ - cum; break; }
        cum += c;
      }
    }
  }
}

// ---------------- EDT axis H (1/thr) + 8-region dense compaction ----------------
// ballot/popc wave prefix + 4-entry LDS scan; ONE ticket atomic per block on one of 8
// region counters (region = blk/600, <=600 serialized tickets each, 8 in parallel).
// Candidates land dense per region -> sel23's read is coalesced. Region capacity N/8 is
// safe by construction (a region's 600 blocks cover exactly N/8 voxels).
__global__ __launch_bounds__(256) void k_dt_h(const float* __restrict__ fin,
                                              float* __restrict__ fout,
                                              const float* __restrict__ kl,
                                              unsigned* __restrict__ cand,
                                              unsigned* __restrict__ sc) {
  const int tid = threadIdx.x;
  const int idx = blockIdx.x * 256 + tid;
  const int pos = (idx / W_) % H_;
  float m = fin[idx];
  for (int r = 1; r < H_; r++) {
    const float r2 = (float)(r * r);
    if (r2 >= m) break;
    const bool okm = (pos - r >= 0), okp = (pos + r < H_);
    if (!okm && !okp) break;
    if (okm) m = fminf(m, fin[idx - r * W_] + r2);
    if (okp) m = fminf(m, fin[idx + r * W_] + r2);
  }
  fout[idx] = m;

  const unsigned key = fkey(kl[idx]);
  const bool has = ((key >> 20) == sc[0]);
  const unsigned long long bal = __ballot(has);
  const int lane = tid & 63;
  const int wid = tid >> 6;
  const unsigned lpre = (unsigned)__popcll(bal & ((1ULL << lane) - 1ULL));
  __shared__ unsigned wcnt[4];
  __shared__ unsigned sbase;
  if (lane == 0) wcnt[wid] = (unsigned)__popcll(bal);
  __syncthreads();
  unsigned woff = 0;
  for (int w = 0; w < wid; w++) woff += wcnt[w];
  const unsigned btot = wcnt[0] + wcnt[1] + wcnt[2] + wcnt[3];
  const int reg = blockIdx.x / HBLK;
  if (tid == 0 && btot) sbase = atomicAdd(&sc[8 + reg], btot);
  __syncthreads();
  if (has) cand[reg * REGCAP + sbase + woff + lpre] = key & 0xFFFFFu;
}

// ---------------- EDT axis W + sqrt (1/thr) + 12+8 radix select in block 0 ----------------
__global__ __launch_bounds__(256) void k_dt_w(const float* __restrict__ fin,
                                              float* __restrict__ fout,
                                              const unsigned* __restrict__ cand,
                                              unsigned* __restrict__ sc) {
  const int idx = blockIdx.x * 256 + threadIdx.x;
  const int pos = idx % W_;
  float m = fin[idx];
  for (int r = 1; r < W_; r++) {
    const float r2 = (float)(r * r);
    if (r2 >= m) break;
    const bool okm = (pos - r >= 0), okp = (pos + r < W_);
    if (!okm && !okp) break;
    if (okm) m = fminf(m, fin[idx - r] + r2);
    if (okp) m = fminf(m, fin[idx + r] + r2);
  }
  fout[idx] = sqrtf(m);

  if (blockIdx.x != 0) return;
  // ---- block 0 tail: rank-select over 8 dense candidate regions (ready last kernel) ----
  const int tid = threadIdx.x;
  const unsigned K = sc[1];
  __shared__ unsigned hist[4096];
  __shared__ unsigned ssum[256];
  __shared__ unsigned h2[256];
  __shared__ unsigned sBA, sKB;
  for (int i = tid; i < 4096; i += 256) hist[i] = 0;
  h2[tid] = 0;
  __syncthreads();
  for (int j = 0; j < 8; j++) {
    const unsigned cj = sc[8 + j];
    const unsigned rb = (unsigned)j * (unsigned)REGCAP;
    for (unsigned i = (unsigned)tid; i < cj; i += 256u)
      atomicAdd(&hist[(cand[rb + i] >> 8) & 0xFFFu], 1u);
  }
  __syncthreads();
  unsigned mine = 0;
#pragma unroll
  for (int i = 0; i < 16; i++) mine += hist[tid * 16 + i];
  ssum[tid] = mine;
  __syncthreads();
  for (int o = 1; o < 256; o <<= 1) {
    const unsigned add = (tid >= o) ? ssum[tid - o] : 0u;
    __syncthreads();
    ssum[tid] += add;
    __syncthreads();
  }
  {
    const unsigned before = ssum[tid] - mine;
    if (before < K && K <= before + mine) {
      unsigned cum = before;
      for (int i = 0; i < 16; i++) {
        const unsigned c = hist[tid * 16 + i];
        if (cum < K && K <= cum + c) { sBA = (unsigned)(tid * 16 + i); sKB = K - cum; break; }
        cum += c;
      }
    }
  }
  __syncthreads();
  const unsigned bA = sBA, KB = sKB;
  for (int j = 0; j < 8; j++) {
    const unsigned cj = sc[8 + j];
    const unsigned rb = (unsigned)j * (unsigned)REGCAP;
    for (unsigned i = (unsigned)tid; i < cj; i += 256u) {
      const unsigned v = cand[rb + i];
      if (((v >> 8) & 0xFFFu) == bA) atomicAdd(&h2[v & 0xFFu], 1u);
    }
  }
  __syncthreads();
  const unsigned mine2 = h2[tid];
  ssum[tid] = mine2;
  __syncthreads();
  for (int o = 1; o < 256; o <<= 1) {
    const unsigned add = (tid >= o) ? ssum[tid - o] : 0u;
    __syncthreads();
    ssum[tid] += add;
    __syncthreads();
  }
  {
    const unsigned before = ssum[tid] - mine2;
    if (before < KB && KB <= before + mine2) {
      const unsigned key = (sc[0] << 20) | (bA << 8) | (unsigned)tid;
      sc[6] = (key & 0x80000000u) ? (key & 0x7FFFFFFFu) : ~key;  // inverse of fkey
    }
  }
}

// ---------------- masked loss at each voxel + block partials (plain stores) ----------------
__global__ __launch_bounds__(256) void k_loss(const float* __restrict__ inp,
                                              const float* __restrict__ kl,
                                              const float* __restrict__ gdist,
                                              const unsigned* __restrict__ sc,
                                              float* __restrict__ psum,
                                              unsigned* __restrict__ pcnt) {
  const int tid = threadIdx.x;
  const int idx = blockIdx.x * 256 + tid;
  const float thr = __uint_as_float(sc[6]);
  float myloss = 0.f;
  unsigned mycnt = 0u;
  if (kl[idx] >= thr) {
    mycnt = 1u;
    const float g = gdist[idx];
    if (g != 0.f) {
      const int ww = idx % W_;
      const int hh = (idx / W_) % H_;
      const int dd = idx / HW_;
      const float p0 = inp[idx];
      const float p1 = inp[N_ + idx];
      // DIRECTIONS in torch-loop order: i outer, j mid, k inner, skipping (0,0,0)
      constexpr int DI[26] = {-1,-1,-1,-1,-1,-1,-1,-1,-1, 0,0,0,0,0,0,0,0, 1,1,1,1,1,1,1,1,1};
      constexpr int DJ[26] = {-1,-1,-1, 0,0,0, 1,1,1, -1,-1,-1, 0,0, 1,1,1, -1,-1,-1, 0,0,0, 1,1,1};
      constexpr int DK[26] = {-1,0,1, -1,0,1, -1,0,1, -1,0,1, -1,1, -1,0,1, -1,0,1, -1,0,1, -1,0,1};
      float klv[26], dst[26];
      float s = 0.f;
#pragma unroll
      for (int t = 0; t < 26; t++) {
        const int nd = dd + DI[t], nh = hh + DJ[t], nw = ww + DK[t];
        const bool inb = ((unsigned)nd < (unsigned)D_) && ((unsigned)nh < (unsigned)H_) &&
                         ((unsigned)nw < (unsigned)W_);
        const int nidx = (nd * H_ + nh) * W_ + nw;
        dst[t] = inb ? gdist[nidx] : 0.f;
        // coordinate masks from the reference's (batch,d,h) indexing bug, specialized to B=1:
        //  i==+1 -> 0; j==+1 -> 0; j==-1 -> only d==0; k==+1 -> only h==159; k==-1 -> only h==0
        bool keep;
        if (DI[t] == 1 || DJ[t] == 1) keep = false;
        else {
          keep = true;
          if (DJ[t] == -1) keep = (dd == 0);
          if (DK[t] == 1) keep = keep && (hh == H_ - 1);
          if (DK[t] == -1) keep = keep && (hh == 0);
        }
        float kt = 0.f;
        if (keep) {
          float t0 = 0.f, t1 = 0.f;
          if (inb) { t0 = inp[nidx]; t1 = inp[N_ + nidx]; }
          const float a0 = (t0 > 0.f) ? t0 * logf(t0) : 0.f;
          const float a1 = (t1 > 0.f) ? t1 * logf(t1) : 0.f;
          const float kldm = 0.5f * ((a0 - t0 * p0) + (a1 - t1 * p1));
          kt = expf(kldm);
        }
        klv[t] = kt;
        s += kt;
      }
      const float denom = (s == 0.f) ? 1.f : s;
      int amin = 0;
      float dmin = dst[0];
#pragma unroll
      for (int t = 1; t < 26; t++) {
        if (dst[t] < dmin) { dmin = dst[t]; amin = t; }  // first-min, like jnp.argmin
      }
      const float yoff = (float)(0.2 / 26.0);
      float bsum = 0.f;
#pragma unroll
      for (int t = 0; t < 26; t++) {
        const float x = klv[t] / denom;
        const float y = (t == amin) ? 0.8f : yoff;
        bsum += fmaxf(x, 0.f) - x * y + log1pf(expf(-fabsf(x)));
      }
      myloss = (fminf(g, 20.f) / 20.f) * (bsum / 26.f);
    }
  }
  __shared__ float ls[256];
  __shared__ unsigned lc[256];
  ls[tid] = myloss;
  lc[tid] = mycnt;
  __syncthreads();
  for (int o = 128; o > 0; o >>= 1) {
    if (tid < o) { ls[tid] += ls[tid + o]; lc[tid] += lc[tid + o]; }
    __syncthreads();
  }
  if (tid == 0) { psum[blockIdx.x] = ls[0]; pcnt[blockIdx.x] = lc[0]; }
}

// ---------------- deterministic final reduce (1 block, vectorized) ----------------
__global__ __launch_bounds__(256) void k_reduce(const float* __restrict__ psum,
                                                const unsigned* __restrict__ pcnt,
                                                float* __restrict__ out) {
  __shared__ float ls[256];
  __shared__ unsigned lc[256];
  const int t = threadIdx.x;
  float s = 0.f;
  unsigned c = 0;
  for (int g = t; g * 4 < NBLK; g += 256) {
    const float4 s4 = *reinterpret_cast<const float4*>(&psum[g * 4]);
    const uint4 c4 = *reinterpret_cast<const uint4*>(&pcnt[g * 4]);
    s += (s4.x + s4.y) + (s4.z + s4.w);
    c += c4.x + c4.y + c4.z + c4.w;
  }
  ls[t] = s;
  lc[t] = c;
  __syncthreads();
  for (int o = 128; o > 0; o >>= 1) {
    if (t < o) { ls[t] += ls[t + o]; lc[t] += lc[t + o]; }
    __syncthreads();
  }
  if (t == 0) out[0] = ls[0] / (float)lc[0];
}

extern "C" void kernel_launch(void* const* d_in, const int* in_sizes, int n_in,
                              void* d_out, int out_size, void* d_ws, size_t ws_size,
                              hipStream_t stream) {
  (void)in_sizes; (void)n_in; (void)out_size; (void)ws_size;
  const float* inp = (const float*)d_in[0];
  const int* tgt = (const int*)d_in[1];
  float* out = (float*)d_out;
  char* ws = (char*)d_ws;

  float* kl = (float*)(ws + OFF_KL);
  float* fA = (float*)(ws + OFF_FA);
  float* fB = (float*)(ws + OFF_FB);
  unsigned* cand = (unsigned*)(ws + OFF_CAND);
  unsigned* g1 = (unsigned*)(ws + OFF_G1);
  unsigned* sc = (unsigned*)(ws + OFF_SC);
  float* ps = (float*)(ws + OFF_PS);
  unsigned* pc = (unsigned*)(ws + OFF_PC);

  k_zero<<<17, 256, 0, stream>>>(g1, sc);
  k_prep<<<HBLK, 256, 0, stream>>>(inp, tgt, kl, fA, g1);
  k_dt_d<<<NBLK, 256, 0, stream>>>(fA, fB, g1, sc);        // EDT D + sel1 (blk0)
  k_dt_h<<<NBLK, 256, 0, stream>>>(fB, fA, kl, cand, sc);  // EDT H + 8-region dense compaction
  k_dt_w<<<NBLK, 256, 0, stream>>>(fA, fB, cand, sc);      // EDT W + sqrt + sel23 (blk0)
  k_loss<<<NBLK, 256, 0, stream>>>(inp, kl, fB, sc, ps, pc);
  k_reduce<<<1, 256, 0, stream>>>(ps, pc, out);
}